// Round 1
// baseline (143.819 us; speedup 1.0000x reference)
//
#include <hip/hip_runtime.h>
#include <math.h>

#define TWO_PI_F 6.28318530717958647692f
#define PI_F     3.14159265358979323846f
#define CE_ROWS  4   // rows per wave, ALL loads issued up front

typedef float f32x4 __attribute__((ext_vector_type(4)));

__device__ __forceinline__ float warp_sum(float s) {
    #pragma unroll
    for (int off = 32; off; off >>= 1) s += __shfl_xor(s, off, 64);
    return s;
}
__device__ __forceinline__ float warp_max(float m) {
    #pragma unroll
    for (int off = 32; off; off >>= 1) m = fmaxf(m, __shfl_xor(m, off, 64));
    return m;
}
__device__ __forceinline__ float max4(f32x4 v) {
    return fmaxf(fmaxf(v.x, v.y), fmaxf(v.z, v.w));
}

// One row's -log_softmax[t] from a register-resident row. Wave-uniform result.
__device__ __forceinline__ float ce_compute(f32x4 v0, f32x4 v1, f32x4 v2, f32x4 v3,
                                            float tail, int t, int nf4, int remBase,
                                            int lane) {
    // extract x[t] from registers (no dependent global load) — R9 verified win
    const int fj   = t >> 2;
    const int slot = t & 3;
    int owner;
    float cand;
    if (fj < nf4) {
        owner = fj & 63;
        const int reg = fj >> 6;
        f32x4 c4 = (reg == 0) ? v0 : (reg == 1) ? v1 : (reg == 2) ? v2 : v3;
        cand = (slot == 0) ? c4.x : (slot == 1) ? c4.y : (slot == 2) ? c4.z : c4.w;
    } else {
        owner = t - remBase;
        cand = tail;
    }
    const float tv = __shfl(cand, owner, 64);

    float m = tail;
    m = fmaxf(m, max4(v0));
    m = fmaxf(m, max4(v1));
    m = fmaxf(m, max4(v2));
    m = fmaxf(m, max4(v3));
    m = warp_max(m);           // max-pass kept: measured ~10us faster than no-max

    float s;
    s  = __expf(v0.x - m) + __expf(v0.y - m) + __expf(v0.z - m) + __expf(v0.w - m);
    s += __expf(v1.x - m) + __expf(v1.y - m) + __expf(v1.z - m) + __expf(v1.w - m);
    s += __expf(v2.x - m) + __expf(v2.y - m) + __expf(v2.z - m) + __expf(v2.w - m);
    s += __expf(v3.x - m) + __expf(v3.y - m) + __expf(v3.z - m) + __expf(v3.w - m);
    s += __expf(tail - m);
    s = warp_sum(s);

    return m + __logf(s) - tv;
}

// Generic CE fallback (C > 1024): two passes with max subtraction.
__device__ float ce_row_generic(const float* __restrict__ rowp, int C, int lane, int t) {
    const float4* row4 = (const float4*)rowp;
    const int nf4 = C >> 2;
    const float tv = rowp[t];
    float m = -INFINITY;
    for (int j = lane; j < nf4; j += 64) {
        float4 x = row4[j];
        m = fmaxf(m, fmaxf(fmaxf(x.x, x.y), fmaxf(x.z, x.w)));
    }
    const int remBase = nf4 << 2;
    if (remBase + lane < C) m = fmaxf(m, rowp[remBase + lane]);
    m = warp_max(m);
    float s = 0.0f;
    for (int j = lane; j < nf4; j += 64) {
        float4 x = row4[j];
        s += __expf(x.x - m) + __expf(x.y - m) + __expf(x.z - m) + __expf(x.w - m);
    }
    if (remBase + lane < C) s += __expf(rowp[remBase + lane] - m);
    s = warp_sum(s);
    return m + __logf(s) - tv;
}

// issue one row's loads into named regs (nontemporal: read-once streaming)
#define LOAD_ROW(rowidx, V0, V1, V2, V3, VT)                                   \
    {                                                                          \
        const float* _p = outputs + (size_t)(rowidx) * (size_t)C;              \
        const f32x4* _q = (const f32x4*)_p;                                    \
        V0 = (j0 < nf4) ? __builtin_nontemporal_load(_q + j0) : NEG;           \
        V1 = (j1 < nf4) ? __builtin_nontemporal_load(_q + j1) : NEG;           \
        V2 = (j2 < nf4) ? __builtin_nontemporal_load(_q + j2) : NEG;           \
        V3 = (j3 < nf4) ? __builtin_nontemporal_load(_q + j3) : NEG;           \
        VT = (remBase + lane < C)                                              \
           ? __builtin_nontemporal_load(_p + remBase + lane) : -INFINITY;      \
    }

// Stage 1: fully unified fused CE + resonance. One block type:
//   - edge gather: 2 threads per edge (lane pair), ONE random phase load each,
//     issued AFTER the 16 CE streaming loads and finished AFTER the CE exp
//     pipeline — the ~900-cycle random-gather latency hides under CE compute.
//     (Previous version: 512 dedicated resonance blocks, latency-exposed.)
//   - CE: 4 rows/wave, ALL 16 dwordx4 loads issued before any compute.
// Grid is exactly max(2E/256, B/16) = 1024 for the bench shape; one plain
// partial store per block (no atomics: same-address atomicAdds measured ~35us
// serialization in R1/R3).
__global__ __launch_bounds__(256) void fused_kernel(
    const float* __restrict__ outputs,
    const int*   __restrict__ targets,
    const float* __restrict__ phase,
    const int*   __restrict__ esrc,
    const int*   __restrict__ edst,
    int B, int C, int N, int E,
    float invB, float scaleE,
    float* __restrict__ ws)
{
    __shared__ float part[4];
    const int lane = threadIdx.x & 63;
    const int wave = threadIdx.x >> 6;

    // ---- edge index loads: issued first, waited on only after CE loads ----
    const int gi = blockIdx.x * blockDim.x + threadIdx.x;
    const bool has_edge = gi < (E << 1);
    int es = 0, ed = 0;
    if (has_edge) {
        const int e = gi >> 1;
        es = esrc[e];
        ed = edst[e];
    }

    const int nf4 = C >> 2;
    const int wbase = (blockIdx.x * 4 + wave) * CE_ROWS;
    float wsum = 0.0f;

    if (nf4 <= 256 && wbase + CE_ROWS <= B) {
        // ---------------- fast path: 4 rows/wave, all loads up front --------
        const int remBase = nf4 << 2;
        const int j0 = lane, j1 = lane + 64, j2 = lane + 128, j3 = lane + 192;
        const f32x4 NEG = {-INFINITY, -INFINITY, -INFINITY, -INFINITY};

        // one 16B load for 4 targets (wbase is a multiple of 4)
        const int4 t4 = *(const int4*)(targets + wbase);

        f32x4 a0, a1, a2, a3; float at;
        f32x4 b0, b1, b2, b3; float bt;
        f32x4 c0, c1, c2, c3; float ct;
        f32x4 d0, d1, d2, d3; float dt;
        LOAD_ROW(wbase + 0, a0, a1, a2, a3, at);
        LOAD_ROW(wbase + 1, b0, b1, b2, b3, bt);
        LOAD_ROW(wbase + 2, c0, c1, c2, c3, ct);
        LOAD_ROW(wbase + 3, d0, d1, d2, d3, dt);

        // issue the dependent random gather now: its latency hides under the
        // ~2000-cycle exp/shuffle pipeline below
        float pv = 0.0f;
        if (has_edge) {
            const int r = (gi & 1) ? ed : es;
            const int c = (gi & 1) ? es : ed;
            pv = phase[(size_t)r * (size_t)N + (size_t)c];
        }

        float acc;
        acc  = ce_compute(a0, a1, a2, a3, at, t4.x, nf4, remBase, lane);
        acc += ce_compute(b0, b1, b2, b3, bt, t4.y, nf4, remBase, lane);
        acc += ce_compute(c0, c1, c2, c3, ct, t4.z, nf4, remBase, lane);
        acc += ce_compute(d0, d1, d2, d3, dt, t4.w, nf4, remBase, lane);

        // finish the edge term (pv long since landed)
        float dterm = 0.0f;
        if (has_edge) {
            const float other = __shfl_xor(pv, 1, 64);
            if (!(gi & 1)) {                       // even lane owns the edge
                float dd = fabsf(pv - other);
                dd = fmodf(dd, TWO_PI_F);
                if (dd > PI_F) dd = TWO_PI_F - dd;
                dterm = dd;
            }
        }
        const float esum = warp_sum(dterm);
        if (lane == 0) wsum = acc * invB + esum * scaleE;
    } else {
        // ---------------- generic fallback ----------------------------------
        float pv = 0.0f;
        if (has_edge) {
            const int r = (gi & 1) ? ed : es;
            const int c = (gi & 1) ? es : ed;
            pv = phase[(size_t)r * (size_t)N + (size_t)c];
        }
        float dterm = 0.0f;
        if (has_edge) {
            const float other = __shfl_xor(pv, 1, 64);
            if (!(gi & 1)) {
                float dd = fabsf(pv - other);
                dd = fmodf(dd, TWO_PI_F);
                if (dd > PI_F) dd = TWO_PI_F - dd;
                dterm = dd;
            }
        }
        const float esum = warp_sum(dterm);

        float acc = 0.0f;
        for (int k = 0; k < CE_ROWS; ++k) {
            const int row = wbase + k;
            if (row < B)
                acc += ce_row_generic(outputs + (size_t)row * (size_t)C,
                                      C, lane, targets[row]);
        }
        if (lane == 0) wsum = acc * invB + esum * scaleE;
    }

    if (lane == 0) part[wave] = wsum;
    __syncthreads();
    if (threadIdx.x == 0)
        ws[blockIdx.x] = part[0] + part[1] + part[2] + part[3];   // plain store
}

// Stage 2: single block (512 threads) reduces all partials.
__global__ __launch_bounds__(512) void reduce_kernel(
    const float* __restrict__ ws, int P, float* __restrict__ out)
{
    float s = 0.0f;
    for (int i = threadIdx.x; i < P; i += 512)
        s += ws[i];
    s = warp_sum(s);
    __shared__ float part[8];
    if ((threadIdx.x & 63) == 0) part[threadIdx.x >> 6] = s;
    __syncthreads();
    if (threadIdx.x == 0) {
        float tot = 0.0f;
        #pragma unroll
        for (int i = 0; i < 8; i++) tot += part[i];
        out[0] = tot;
    }
}

extern "C" void kernel_launch(void* const* d_in, const int* in_sizes, int n_in,
                              void* d_out, int out_size, void* d_ws, size_t ws_size,
                              hipStream_t stream) {
    const float* outputs = (const float*)d_in[0];
    const int*   targets = (const int*)d_in[1];
    const float* phase   = (const float*)d_in[2];
    const int*   esrc    = (const int*)d_in[3];
    const int*   edst    = (const int*)d_in[4];

    const int B = in_sizes[1];
    const int C = in_sizes[0] / B;
    const int E = in_sizes[3];
    int N = 1;
    while ((long long)N * (long long)N < (long long)in_sizes[2]) N++;

    const int rows_per_block = 4 * CE_ROWS;                        // 16
    const int ce_blocks   = (B + rows_per_block - 1) / rows_per_block;  // 1024
    const int edge_blocks = (2 * E + 255) / 256;                   // 1024
    const int grid = (ce_blocks > edge_blocks) ? ce_blocks : edge_blocks;

    float* ws = (float*)d_ws;

    fused_kernel<<<grid, 256, 0, stream>>>(outputs, targets, phase, esrc, edst,
                                           B, C, N, E,
                                           1.0f / (float)B, 0.1f / (float)E,
                                           ws);
    reduce_kernel<<<1, 512, 0, stream>>>(ws, grid, (float*)d_out);
}